// Round 6
// baseline (507.749 us; speedup 1.0000x reference)
//
#include <hip/hip_runtime.h>
#include <math.h>

#define B_  4
#define L_  8192
#define D_  512
#define BL_ (B_*L_)
#define TOK 16
#define XS  18            // row stride: 8B-aligned float2, 4-way max on stage writes
#define KC  64
#define NCH (D_/KC)

// ---------------------------------------------------------------------------
// Signal + e:
//   content = sigmoid(relu(x@W1+b1)@W2+b2)
//   pf      = groupedconv(x)+bc  (per K-chunk into LDS)
//   bscore  = sigmoid(relu([x,pf]@Wb1+bb1)@Wb2+bb2)
//   signal  = content*(1-bscore)*mask;  e = mask^2 * sum(x^2)
// 16 tokens/block, 2048 blocks (8/CU -> 32 waves/CU). Thread = 2 tok x 4 j.
// ---------------------------------------------------------------------------
__global__ __launch_bounds__(256, 8) void k_signal(
    const float* __restrict__ x, const float* __restrict__ mask,
    const float* __restrict__ W1, const float* __restrict__ b1,
    const float* __restrict__ W2, const float* __restrict__ b2,
    const float* __restrict__ Wc, const float* __restrict__ bc,
    const float* __restrict__ Wb1, const float* __restrict__ bb1,
    const float* __restrict__ Wb2, const float* __restrict__ bb2,
    float* __restrict__ signal, float* __restrict__ e)
{
  __shared__ float xt[KC][XS];   // [k][tok]; col 16 = l0-1, col 17 = l0+16
  __shared__ float pf[32][XS];   // conv out chunk [oo][tok]

  const int t   = threadIdx.x;
  const int blk = blockIdx.x;          // 2048 = 4 b x 512 tiles
  const int b   = blk >> 9;
  const int l0  = (blk & 511) * TOK;
  const float* xb = x + (size_t)b * L_ * D_;

  const int jq = t & 31, tw = t >> 5;
  const int j0 = jq << 2, tok0 = tw << 1;

  // staging / e role: one float4 per chunk
  const int stok = t >> 4, skk = t & 15;
  // conv role: 32 out-ch per chunk, 2 tokens per thread
  const int oo_c  = t >> 3;            // 0..31
  const int tokq  = t & 7;
  const int cb_c  = (oo_c >> 1) << 2;  // relative in-channel base 0..60
  const int tok0c = tokq << 1;

  float a1[2][4], a2[2][4];
#pragma unroll
  for (int i = 0; i < 2; ++i)
#pragma unroll
    for (int j = 0; j < 4; ++j) { a1[i][j] = 0.f; a2[i][j] = 0.f; }
  float esacc = 0.f;

  for (int c = 0; c < NCH; ++c) {
    const int kc = c << 6;
    __syncthreads();                   // xt/pf free of previous readers

    // ---- stage x chunk transposed; accumulate sum(x^2) ----
    {
      const float4 v = *reinterpret_cast<const float4*>(
          xb + (size_t)(l0 + stok) * D_ + kc + (skk << 2));
      esacc = fmaf(v.x, v.x, esacc); esacc = fmaf(v.y, v.y, esacc);
      esacc = fmaf(v.z, v.z, esacc); esacc = fmaf(v.w, v.w, esacc);
      const int r = skk << 2;
      xt[r + 0][stok] = v.x; xt[r + 1][stok] = v.y;
      xt[r + 2][stok] = v.z; xt[r + 3][stok] = v.w;
    }
    if (t < 32) {
      const int hh = t >> 4, kk = t & 15;
      const int l = hh ? (l0 + TOK) : (l0 - 1);
      float4 v = make_float4(0.f, 0.f, 0.f, 0.f);
      if (l >= 0 && l < L_)
        v = *reinterpret_cast<const float4*>(xb + (size_t)l * D_ + kc + (kk << 2));
      const int r = kk << 2, col = TOK + hh;
      xt[r + 0][col] = v.x; xt[r + 1][col] = v.y;
      xt[r + 2][col] = v.z; xt[r + 3][col] = v.w;
    }
    __syncthreads();

    // ---- conv: this chunk's 32 output channels, 2 tokens/thread ----
    {
      const int o = (c << 5) + oo_c;
      const float* wcp = Wc + o * 12;
      const float bco = bc[o];
      float acc0 = bco, acc1 = bco;
      const int tm1 = (tok0c == 0) ? TOK : tok0c - 1;
      const int tp2 = (tok0c == TOK - 2) ? TOK + 1 : tok0c + 2;
#pragma unroll
      for (int i = 0; i < 4; ++i) {
        const float w0 = wcp[i * 3 + 0], w1 = wcp[i * 3 + 1], w2 = wcp[i * 3 + 2];
        const float* row = &xt[cb_c + i][0];
        const float v0 = row[tm1], v1 = row[tok0c], v2 = row[tok0c + 1],
                    v3 = row[tp2];
        acc0 = fmaf(v2, w2, fmaf(v1, w1, fmaf(v0, w0, acc0)));
        acc1 = fmaf(v3, w2, fmaf(v2, w1, fmaf(v1, w0, acc1)));
      }
      pf[oo_c][tok0c]     = acc0;
      pf[oo_c][tok0c + 1] = acc1;
    }

    // ---- GEMM x-part: both matrices ----
    {
      const float* w1p = W1  + (size_t)kc * 128 + j0;
      const float* wbp = Wb1 + (size_t)kc * 128 + j0;
#pragma unroll 4
      for (int k = 0; k < KC; ++k) {
        const float4 w1 = *reinterpret_cast<const float4*>(w1p + (size_t)k * 128);
        const float4 wb = *reinterpret_cast<const float4*>(wbp + (size_t)k * 128);
        const float2 xv = *reinterpret_cast<const float2*>(&xt[k][tok0]);
        a1[0][0] = fmaf(xv.x, w1.x, a1[0][0]);
        a1[0][1] = fmaf(xv.x, w1.y, a1[0][1]);
        a1[0][2] = fmaf(xv.x, w1.z, a1[0][2]);
        a1[0][3] = fmaf(xv.x, w1.w, a1[0][3]);
        a1[1][0] = fmaf(xv.y, w1.x, a1[1][0]);
        a1[1][1] = fmaf(xv.y, w1.y, a1[1][1]);
        a1[1][2] = fmaf(xv.y, w1.z, a1[1][2]);
        a1[1][3] = fmaf(xv.y, w1.w, a1[1][3]);
        a2[0][0] = fmaf(xv.x, wb.x, a2[0][0]);
        a2[0][1] = fmaf(xv.x, wb.y, a2[0][1]);
        a2[0][2] = fmaf(xv.x, wb.z, a2[0][2]);
        a2[0][3] = fmaf(xv.x, wb.w, a2[0][3]);
        a2[1][0] = fmaf(xv.y, wb.x, a2[1][0]);
        a2[1][1] = fmaf(xv.y, wb.y, a2[1][1]);
        a2[1][2] = fmaf(xv.y, wb.z, a2[1][2]);
        a2[1][3] = fmaf(xv.y, wb.w, a2[1][3]);
      }
    }
    __syncthreads();                   // pf writes visible

    // ---- GEMM pf-part ----
    {
      const float* wpp = Wb1 + (size_t)(512 + (c << 5)) * 128 + j0;
#pragma unroll 4
      for (int oo = 0; oo < 32; ++oo) {
        const float4 wp = *reinterpret_cast<const float4*>(wpp + (size_t)oo * 128);
        const float2 pv = *reinterpret_cast<const float2*>(&pf[oo][tok0]);
        a2[0][0] = fmaf(pv.x, wp.x, a2[0][0]);
        a2[0][1] = fmaf(pv.x, wp.y, a2[0][1]);
        a2[0][2] = fmaf(pv.x, wp.z, a2[0][2]);
        a2[0][3] = fmaf(pv.x, wp.w, a2[0][3]);
        a2[1][0] = fmaf(pv.y, wp.x, a2[1][0]);
        a2[1][1] = fmaf(pv.y, wp.y, a2[1][1]);
        a2[1][2] = fmaf(pv.y, wp.z, a2[1][2]);
        a2[1][3] = fmaf(pv.y, wp.w, a2[1][3]);
      }
    }
  }

  // ---- epilogue: relu, project, cross-jq reduce, sigmoid ----
  {
    float b1v[4], w2v[4], bbv[4], wv2[4];
#pragma unroll
    for (int jj = 0; jj < 4; ++jj) {
      b1v[jj] = b1[j0 + jj];  w2v[jj] = W2[j0 + jj];
      bbv[jj] = bb1[j0 + jj]; wv2[jj] = Wb2[j0 + jj];
    }
    const float bias2 = b2[0], biasb2 = bb2[0];
#pragma unroll
    for (int i = 0; i < 2; ++i) {
      float p1 = 0.f, p2 = 0.f;
#pragma unroll
      for (int jj = 0; jj < 4; ++jj) {
        const float h1 = a1[i][jj] + b1v[jj];
        if (h1 > 0.f) p1 = fmaf(h1, w2v[jj], p1);
        const float h2 = a2[i][jj] + bbv[jj];
        if (h2 > 0.f) p2 = fmaf(h2, wv2[jj], p2);
      }
#pragma unroll
      for (int off = 1; off < 32; off <<= 1) {
        p1 += __shfl_xor(p1, off, 64);
        p2 += __shfl_xor(p2, off, 64);
      }
      if (jq == 0) {
        const int gi = b * L_ + l0 + tok0 + i;
        const float content = 1.f / (1.f + expf(-(p1 + bias2)));
        const float bscore  = 1.f / (1.f + expf(-(p2 + biasb2)));
        signal[gi] = content * (1.f - bscore) * mask[gi];
      }
    }
  }

  // ---- e epilogue: butterfly over the 16 skk lanes of each token ----
  {
    float es = esacc;
    es += __shfl_xor(es, 1, 64);
    es += __shfl_xor(es, 2, 64);
    es += __shfl_xor(es, 4, 64);
    es += __shfl_xor(es, 8, 64);
    if (skk == 0) {
      const int gi = b * L_ + l0 + stok;
      const float m = mask[gi];
      e[gi] = m * m * es;
    }
  }
}

// ---------------------------------------------------------------------------
// Fused quantile + enforce. One block (1024 thr) per batch row.
// ---------------------------------------------------------------------------
__device__ __forceinline__ int chain_sim(unsigned long long w, int from) {
  int last = -1;
  while (from < 64) {
    const unsigned long long m = w & (~0ull << from);
    if (m == 0ull) break;
    const int p = __ffsll(m) - 1;
    last = p;
    from = p + 4;
  }
  return last;
}

__global__ __launch_bounds__(1024) void k_select(
    const float* __restrict__ signal,
    int* __restrict__ starts, int* __restrict__ nlast, float* __restrict__ bounds)
{
  __shared__ unsigned int bins[4][256];
  __shared__ unsigned int sel_prefix;
  __shared__ int sel_rank;
  __shared__ float sh_thr;
  __shared__ unsigned int wmin[16];
  __shared__ int wcnt[16];
  __shared__ unsigned long long cw[128];
  __shared__ unsigned char nb[L_];
  __shared__ signed char tbl[128][4];
  __shared__ int st_in[128];
  __shared__ int tsum[256];
  __shared__ int offs[257];

  const int b = blockIdx.x, t = threadIdx.x;
  const int wv = t >> 6, lane = t & 63;
  const float* s = signal + b * L_;

  float val[8];
  unsigned int key[8];
#pragma unroll
  for (int i = 0; i < 8; ++i) {
    val[i] = s[(i << 10) + t];
    const unsigned int u = __float_as_uint(val[i]);
    key[i] = (u & 0x80000000u) ? ~u : (u | 0x80000000u);
  }

  // ---- radix select rank 5733 = floor(0.7*(L-1)) ----
  if (t == 0) { sel_prefix = 0u; sel_rank = 5733; }
  __syncthreads();
  for (int round = 0; round < 4; ++round) {
    reinterpret_cast<unsigned int*>(bins)[t] = 0u;
    __syncthreads();
    const unsigned int pre = sel_prefix;
    const int shift = 24 - 8 * round;
#pragma unroll
    for (int i = 0; i < 8; ++i) {
      if (round == 0 || (key[i] >> (shift + 8)) == pre)
        atomicAdd(&bins[t >> 8][(key[i] >> shift) & 255u], 1u);
    }
    __syncthreads();
    if (t < 256)
      bins[0][t] = bins[0][t] + bins[1][t] + bins[2][t] + bins[3][t];
    __syncthreads();
    if (t < 64) {
      const unsigned int c0 = bins[0][(t << 2) + 0], c1 = bins[0][(t << 2) + 1];
      const unsigned int c2 = bins[0][(t << 2) + 2], c3 = bins[0][(t << 2) + 3];
      const unsigned int lsum = c0 + c1 + c2 + c3;
      unsigned int run = lsum;
#pragma unroll
      for (int off = 1; off < 64; off <<= 1) {
        const unsigned int v = __shfl_up(run, off, 64);
        if (t >= off) run += v;
      }
      const int r = sel_rank;
      if (r >= (int)(run - lsum) && r < (int)run) {
        int rr = r - (int)(run - lsum);
        unsigned int cbin;
        if (rr < (int)c0) { cbin = 0; }
        else if (rr < (int)(c0 + c1)) { cbin = 1; rr -= (int)c0; }
        else if (rr < (int)(c0 + c1 + c2)) { cbin = 2; rr -= (int)(c0 + c1); }
        else { cbin = 3; rr -= (int)(c0 + c1 + c2); }
        sel_rank = rr;
        sel_prefix = (pre << 8) | ((unsigned int)(t << 2) | cbin);
      }
    }
    __syncthreads();
  }
  const unsigned int k0 = sel_prefix;

  // ---- successor: count <=k0 and min of keys > k0 (tie-safe) ----
  {
    int cle = 0;
    unsigned int mgt = 0xFFFFFFFFu;
#pragma unroll
    for (int i = 0; i < 8; ++i) {
      if (key[i] <= k0) ++cle;
      else mgt = min(mgt, key[i]);
    }
#pragma unroll
    for (int off = 1; off < 64; off <<= 1) {
      cle += __shfl_xor(cle, off, 64);
      mgt = min(mgt, (unsigned int)__shfl_xor((int)mgt, off, 64));
    }
    if (lane == 0) { wcnt[wv] = cle; wmin[wv] = mgt; }
    __syncthreads();
    if (t == 0) {
      int C = 0; unsigned int M = 0xFFFFFFFFu;
      for (int g = 0; g < 16; ++g) { C += wcnt[g]; M = min(M, wmin[g]); }
      const unsigned int k1 = (C >= 5735) ? k0 : M;
      const unsigned int u0 = (k0 & 0x80000000u) ? (k0 & 0x7fffffffu) : ~k0;
      const unsigned int u1 = (k1 & 0x80000000u) ? (k1 & 0x7fffffffu) : ~k1;
      const float v0 = __uint_as_float(u0);
      const float v1 = __uint_as_float(u1);
      const float g = 0.7f * 8191.0f - 5733.0f;
      sh_thr = v0 + g * (v1 - v0);
    }
    __syncthreads();
  }
  const float thr = sh_thr;

  // ---- candidate bitmap from register values ----
#pragma unroll
  for (int i = 0; i < 8; ++i) {
    const unsigned long long m = __ballot(val[i] < thr);
    if (lane == 0) cw[(i << 4) + wv] = m;
  }
  {
    const int base = t << 3;
#pragma unroll
    for (int i = 0; i < 8; ++i) nb[base + i] = 0;
  }
  __syncthreads();
  if (t == 0) cw[127] |= (1ull << 63);   // forced candidate at L-1
  __syncthreads();

  // ---- (1) per-64-block transition tables ----
  if (t < 512) {
    const int blk = t >> 2, cls = t & 3;
    tbl[blk][cls] = (signed char)chain_sim(cw[blk], cls);
  }
  __syncthreads();

  // ---- (2) serial 128-step state scan ----
  if (t == 0) {
    int st = 0;
    for (int blk = 0; blk < 128; ++blk) {
      const int bs = blk << 6;
      st_in[blk] = st;
      int pl;
      if (blk == 0) {
        pl = chain_sim(cw[0], 4);
      } else {
        int off = st + 4 - bs;
        if (off < 0) off = 0;
        pl = tbl[blk][off];
      }
      if (pl >= 0) st = bs + pl;
    }
  }
  __syncthreads();

  // ---- (3) parallel emission of acceptance + split bytes ----
  if (t < 128) {
    const int bs = t << 6;
    const unsigned long long w = cw[t];
    int st = st_in[t];
    int from = st + 4 - bs;
    if (from < 0) from = 0;
    while (from < 64) {
      const unsigned long long m = w & (~0ull << from);
      if (m == 0ull) break;
      const int p_rel = __ffsll(m) - 1;
      const int p = bs + p_rel;
      nb[p] = 1;
      const int ps = p - st;
      const int k = (ps + 15) >> 4;
      if (k > 1) {
        int sz = ps / k; if (sz < 1) sz = 1;
        for (int j = 1; j < k; ++j) nb[st + j * sz] = 1;
      }
      st = p;
      from = p_rel + 4;
    }
  }
  __syncthreads();

  // ---- prefix scan -> starts / nlast / bounds ----
  if (t < 256) {
    const int base = t << 5;
    int ls = 0;
    for (int i = 0; i < 32; ++i) ls += nb[base + i];
    tsum[t] = ls;
  }
  __syncthreads();
  if (t == 0) {
    int r = 0;
    for (int i = 0; i < 256; ++i) { offs[i] = r; r += tsum[i]; }
    offs[256] = r;
  }
  __syncthreads();
  if (t < 256) {
    const int base = t << 5;
    int run = offs[t];
    for (int i = 0; i < 32; ++i) {
      run += nb[base + i];
      if (nb[base + i]) starts[b * L_ + run] = base + i;
    }
  }
  if (t == 0) { starts[b * L_ + 0] = 0; nlast[b] = offs[256]; }
  __syncthreads();
  const int total = offs[256];
  for (int i = t; i < L_; i += 1024)
    bounds[b * L_ + i] = (i >= 1 && i <= total) ? 1.0f : 0.0f;
}

// ---------------------------------------------------------------------------
// Segment softmax-merge: one wave per segment id; dead sids write zeros.
// ---------------------------------------------------------------------------
__global__ __launch_bounds__(64) void k_merge(const float* __restrict__ x,
    const float* __restrict__ mask, const float* __restrict__ e,
    const int* __restrict__ starts, const int* __restrict__ nlast,
    float* __restrict__ merged)
{
  const int idx = blockIdx.x;
  const int b   = idx >> 13;
  const int sid = idx & (L_ - 1);
  const int n = nlast[b];
  const int lane = threadIdx.x;
  const int c0 = lane << 3;
  float* o = merged + (size_t)(b * L_ + sid) * D_ + c0;
  if (sid > n) {
    const float4 z = make_float4(0.f, 0.f, 0.f, 0.f);
    reinterpret_cast<float4*>(o)[0] = z;
    reinterpret_cast<float4*>(o)[1] = z;
    return;
  }
  const int t0 = starts[b * L_ + sid];
  const int t1 = (sid < n) ? starts[b * L_ + sid + 1] : L_;
  const float* eb = e + b * L_;

  float mx = -INFINITY;
  for (int p = t0; p < t1; ++p) mx = fmaxf(mx, eb[p]);
  float den = 0.f;
  for (int p = t0; p < t1; ++p) den += expf(eb[p] - mx);

  float acc[8] = {0,0,0,0,0,0,0,0};
  for (int p = t0; p < t1; ++p) {
    const float wn = expf(eb[p] - mx) / den;
    const float sc = wn * mask[b * L_ + p];
    const float* xr = x + ((size_t)(b * L_ + p)) * D_ + c0;
    const float4 u0 = reinterpret_cast<const float4*>(xr)[0];
    const float4 u1 = reinterpret_cast<const float4*>(xr)[1];
    acc[0] = fmaf(sc, u0.x, acc[0]); acc[1] = fmaf(sc, u0.y, acc[1]);
    acc[2] = fmaf(sc, u0.z, acc[2]); acc[3] = fmaf(sc, u0.w, acc[3]);
    acc[4] = fmaf(sc, u1.x, acc[4]); acc[5] = fmaf(sc, u1.y, acc[5]);
    acc[6] = fmaf(sc, u1.z, acc[6]); acc[7] = fmaf(sc, u1.w, acc[7]);
  }
  reinterpret_cast<float4*>(o)[0] = make_float4(acc[0], acc[1], acc[2], acc[3]);
  reinterpret_cast<float4*>(o)[1] = make_float4(acc[4], acc[5], acc[6], acc[7]);
}

// ---------------------------------------------------------------------------
extern "C" void kernel_launch(void* const* d_in, const int* in_sizes, int n_in,
                              void* d_out, int out_size, void* d_ws, size_t ws_size,
                              hipStream_t stream) {
  (void)in_sizes; (void)n_in; (void)out_size; (void)ws_size;
  const float* x    = (const float*)d_in[0];
  const float* mask = (const float*)d_in[1];
  const float* W1   = (const float*)d_in[2];
  const float* b1   = (const float*)d_in[3];
  const float* W2   = (const float*)d_in[4];
  const float* b2   = (const float*)d_in[5];
  const float* Wc   = (const float*)d_in[6];
  const float* bc   = (const float*)d_in[7];
  const float* Wb1  = (const float*)d_in[8];
  const float* bb1  = (const float*)d_in[9];
  const float* Wb2  = (const float*)d_in[10];
  const float* bb2  = (const float*)d_in[11];

  float* merged = (float*)d_out;
  float* bounds = (float*)d_out + (size_t)BL_ * D_;

  char* ws = (char*)d_ws;
  float* signal = (float*)(ws);
  float* e      = (float*)(ws + (size_t)BL_ * 4);
  int*   starts = (int*)  (ws + (size_t)BL_ * 8);
  int*   nlast  = (int*)  (ws + (size_t)BL_ * 12);

  k_signal<<<BL_ / TOK, 256, 0, stream>>>(x, mask, W1, b1, W2, b2, Wc, bc,
                                          Wb1, bb1, Wb2, bb2, signal, e);
  k_select<<<B_, 1024, 0, stream>>>(signal, starts, nlast, bounds);
  k_merge<<<BL_, 64, 0, stream>>>(x, mask, e, starts, nlast, merged);
}

// Round 7
// 316.062 us; speedup vs baseline: 1.6065x; 1.6065x over previous
//
#include <hip/hip_runtime.h>
#include <math.h>

#define B_  4
#define L_  8192
#define D_  512
#define BL_ (B_*L_)
#define TOK 32
#define XS  36            // xt/pf row stride: 16B-aligned, ==4 mod 32
#define KC  16
#define NCH (D_/KC)

// ---------------------------------------------------------------------------
// Signal + e, weights staged in LDS (one fetch per block, not per wave):
//   content = sigmoid(relu(x@W1+b1)@W2+b2)
//   pf      = groupedconv(x)+bc  (per K-chunk into LDS)
//   bscore  = sigmoid(relu([x,pf]@Wb1+bb1)@Wb2+bb2)
//   signal  = content*(1-bscore)*mask;  e = mask^2 * sum(x^2)
// 32 tokens/block, 1024 blocks (4/CU). Thread = (jq,tw) -> 4 tok x 4 j.
// Inner loop: 3 LDS b128 reads (2 broadcast) vs 32 FMA -> VALU-bound.
// ---------------------------------------------------------------------------
__global__ __launch_bounds__(256, 4) void k_signal(
    const float* __restrict__ x, const float* __restrict__ mask,
    const float* __restrict__ W1, const float* __restrict__ b1,
    const float* __restrict__ W2, const float* __restrict__ b2,
    const float* __restrict__ Wc, const float* __restrict__ bc,
    const float* __restrict__ Wb1, const float* __restrict__ bb1,
    const float* __restrict__ Wb2, const float* __restrict__ bb2,
    float* __restrict__ signal, float* __restrict__ e)
{
  __shared__ float ws1[KC][128];   // W1 chunk rows kc..kc+15
  __shared__ float wsb[KC][128];   // Wb1 x-part chunk
  __shared__ float wsp[8][128];    // Wb1 pf-part chunk (8 conv channels/chunk)
  __shared__ float xt[KC][XS];     // x transposed; col 32 = l0-1, 33 = l0+32
  __shared__ float pf[8][XS];      // conv out chunk

  const int t   = threadIdx.x;
  const int blk = blockIdx.x;          // 1024 = 4 b x 256 tiles
  const int b   = blk >> 8;
  const int l0  = (blk & 255) * TOK;
  const float* xb = x + (size_t)b * L_ * D_;

  const int jq = t & 31, tw = t >> 5;
  const int j0 = jq << 2, tok0 = tw << 2;

  // x-staging / e role (t < 128): one float4 per chunk
  const int stok = t >> 2, skk = t & 3;
  // conv role: 8 out-ch per chunk, 1 token per thread
  const int oo_c  = t >> 5;            // 0..7
  const int tokc  = t & 31;
  const int cb_c  = (oo_c >> 1) << 2;  // rel in-channel base {0,4,8,12}

  float a1[4][4], a2[4][4];
#pragma unroll
  for (int i = 0; i < 4; ++i)
#pragma unroll
    for (int j = 0; j < 4; ++j) { a1[i][j] = 0.f; a2[i][j] = 0.f; }
  float esacc = 0.f;

  for (int c = 0; c < NCH; ++c) {
    const int kc = c << 4;
    __syncthreads();                   // previous chunk fully consumed

    // ---- stage weights: ws1(512 f4) + wsb(512 f4) + wsp(256 f4) ----
    {
      const int row = t >> 5, c4 = (t & 31) << 2;
      {  // ws1 rows 0..7 / 8..15
        const float4 v0 = *reinterpret_cast<const float4*>(W1 + (size_t)(kc + row) * 128 + c4);
        const float4 v1 = *reinterpret_cast<const float4*>(W1 + (size_t)(kc + 8 + row) * 128 + c4);
        *reinterpret_cast<float4*>(&ws1[row][c4]) = v0;
        *reinterpret_cast<float4*>(&ws1[8 + row][c4]) = v1;
      }
      {  // wsb
        const float4 v0 = *reinterpret_cast<const float4*>(Wb1 + (size_t)(kc + row) * 128 + c4);
        const float4 v1 = *reinterpret_cast<const float4*>(Wb1 + (size_t)(kc + 8 + row) * 128 + c4);
        *reinterpret_cast<float4*>(&wsb[row][c4]) = v0;
        *reinterpret_cast<float4*>(&wsb[8 + row][c4]) = v1;
      }
      {  // wsp: conv-out channels c*8 .. c*8+7
        const float4 v0 = *reinterpret_cast<const float4*>(
            Wb1 + (size_t)(512 + (c << 3) + row) * 128 + c4);
        if (row < 8) *reinterpret_cast<float4*>(&wsp[row][c4]) = v0;
      }
    }

    // ---- stage x chunk transposed; accumulate sum(x^2) ----
    if (t < 128) {
      const float4 v = *reinterpret_cast<const float4*>(
          xb + (size_t)(l0 + stok) * D_ + kc + (skk << 2));
      esacc = fmaf(v.x, v.x, esacc); esacc = fmaf(v.y, v.y, esacc);
      esacc = fmaf(v.z, v.z, esacc); esacc = fmaf(v.w, v.w, esacc);
      const int r = skk << 2;
      xt[r + 0][stok] = v.x; xt[r + 1][stok] = v.y;
      xt[r + 2][stok] = v.z; xt[r + 3][stok] = v.w;
    } else if (t < 136) {
      const int q = t - 128;
      const int hh = q >> 2, kk = q & 3;
      const int l = hh ? (l0 + TOK) : (l0 - 1);
      float4 v = make_float4(0.f, 0.f, 0.f, 0.f);
      if (l >= 0 && l < L_)
        v = *reinterpret_cast<const float4*>(xb + (size_t)l * D_ + kc + (kk << 2));
      const int r = kk << 2, col = TOK + hh;
      xt[r + 0][col] = v.x; xt[r + 1][col] = v.y;
      xt[r + 2][col] = v.z; xt[r + 3][col] = v.w;
    }
    __syncthreads();

    // ---- conv: 8 output channels x 32 tokens, 1 per thread ----
    {
      const int o = (c << 3) + oo_c;
      const float* wcp = Wc + o * 12;
      const float4 wq0 = *reinterpret_cast<const float4*>(wcp);
      const float4 wq1 = *reinterpret_cast<const float4*>(wcp + 4);
      const float4 wq2 = *reinterpret_cast<const float4*>(wcp + 8);
      const float wc12[12] = {wq0.x, wq0.y, wq0.z, wq0.w, wq1.x, wq1.y,
                              wq1.z, wq1.w, wq2.x, wq2.y, wq2.z, wq2.w};
      float acc = bc[o];
      const int tm1 = (tokc == 0) ? TOK : tokc - 1;
      const int tp1 = (tokc == TOK - 1) ? TOK + 1 : tokc + 1;
#pragma unroll
      for (int i = 0; i < 4; ++i) {
        const float* row = &xt[cb_c + i][0];
        acc = fmaf(row[tm1],  wc12[i * 3 + 0], acc);
        acc = fmaf(row[tokc], wc12[i * 3 + 1], acc);
        acc = fmaf(row[tp1],  wc12[i * 3 + 2], acc);
      }
      pf[oo_c][tokc] = acc;
    }

    // ---- GEMM x-part from LDS weights ----
#pragma unroll 4
    for (int k = 0; k < KC; ++k) {
      const float4 w1 = *reinterpret_cast<const float4*>(&ws1[k][j0]);
      const float4 wb = *reinterpret_cast<const float4*>(&wsb[k][j0]);
      const float4 xv = *reinterpret_cast<const float4*>(&xt[k][tok0]);
      const float xs4[4] = {xv.x, xv.y, xv.z, xv.w};
#pragma unroll
      for (int i = 0; i < 4; ++i) {
        a1[i][0] = fmaf(xs4[i], w1.x, a1[i][0]);
        a1[i][1] = fmaf(xs4[i], w1.y, a1[i][1]);
        a1[i][2] = fmaf(xs4[i], w1.z, a1[i][2]);
        a1[i][3] = fmaf(xs4[i], w1.w, a1[i][3]);
        a2[i][0] = fmaf(xs4[i], wb.x, a2[i][0]);
        a2[i][1] = fmaf(xs4[i], wb.y, a2[i][1]);
        a2[i][2] = fmaf(xs4[i], wb.z, a2[i][2]);
        a2[i][3] = fmaf(xs4[i], wb.w, a2[i][3]);
      }
    }
    __syncthreads();                   // pf writes visible

    // ---- GEMM pf-part from LDS weights ----
#pragma unroll 4
    for (int oo = 0; oo < 8; ++oo) {
      const float4 wp = *reinterpret_cast<const float4*>(&wsp[oo][j0]);
      const float4 pv = *reinterpret_cast<const float4*>(&pf[oo][tok0]);
      const float ps4[4] = {pv.x, pv.y, pv.z, pv.w};
#pragma unroll
      for (int i = 0; i < 4; ++i) {
        a2[i][0] = fmaf(ps4[i], wp.x, a2[i][0]);
        a2[i][1] = fmaf(ps4[i], wp.y, a2[i][1]);
        a2[i][2] = fmaf(ps4[i], wp.z, a2[i][2]);
        a2[i][3] = fmaf(ps4[i], wp.w, a2[i][3]);
      }
    }
  }

  // ---- epilogue: relu, project, cross-jq reduce, sigmoid ----
  {
    float b1v[4], w2v[4], bbv[4], wv2[4];
#pragma unroll
    for (int jj = 0; jj < 4; ++jj) {
      b1v[jj] = b1[j0 + jj];  w2v[jj] = W2[j0 + jj];
      bbv[jj] = bb1[j0 + jj]; wv2[jj] = Wb2[j0 + jj];
    }
    const float bias2 = b2[0], biasb2 = bb2[0];
#pragma unroll
    for (int i = 0; i < 4; ++i) {
      float p1 = 0.f, p2 = 0.f;
#pragma unroll
      for (int jj = 0; jj < 4; ++jj) {
        const float h1 = a1[i][jj] + b1v[jj];
        if (h1 > 0.f) p1 = fmaf(h1, w2v[jj], p1);
        const float h2 = a2[i][jj] + bbv[jj];
        if (h2 > 0.f) p2 = fmaf(h2, wv2[jj], p2);
      }
#pragma unroll
      for (int off = 1; off < 32; off <<= 1) {
        p1 += __shfl_xor(p1, off, 64);
        p2 += __shfl_xor(p2, off, 64);
      }
      if (jq == 0) {
        const int gi = b * L_ + l0 + tok0 + i;
        const float content = 1.f / (1.f + expf(-(p1 + bias2)));
        const float bscore  = 1.f / (1.f + expf(-(p2 + biasb2)));
        signal[gi] = content * (1.f - bscore) * mask[gi];
      }
    }
  }

  // ---- e epilogue: reduce over the 4 skk lanes of each token ----
  if (t < 128) {
    float es = esacc;
    es += __shfl_xor(es, 1, 64);
    es += __shfl_xor(es, 2, 64);
    if (skk == 0) {
      const int gi = b * L_ + l0 + stok;
      const float m = mask[gi];
      e[gi] = m * m * es;
    }
  }
}

// ---------------------------------------------------------------------------
// Fused quantile + enforce. One block (1024 thr) per batch row.
// ---------------------------------------------------------------------------
__device__ __forceinline__ int chain_sim(unsigned long long w, int from) {
  int last = -1;
  while (from < 64) {
    const unsigned long long m = w & (~0ull << from);
    if (m == 0ull) break;
    const int p = __ffsll(m) - 1;
    last = p;
    from = p + 4;
  }
  return last;
}

__global__ __launch_bounds__(1024) void k_select(
    const float* __restrict__ signal,
    int* __restrict__ starts, int* __restrict__ nlast, float* __restrict__ bounds)
{
  __shared__ unsigned int bins[4][256];
  __shared__ unsigned int sel_prefix;
  __shared__ int sel_rank;
  __shared__ float sh_thr;
  __shared__ unsigned int wmin[16];
  __shared__ int wcnt[16];
  __shared__ unsigned long long cw[128];
  __shared__ unsigned char nb[L_];
  __shared__ signed char tbl[128][4];
  __shared__ int st_in[128];
  __shared__ int tsum[256];
  __shared__ int offs[257];

  const int b = blockIdx.x, t = threadIdx.x;
  const int wv = t >> 6, lane = t & 63;
  const float* s = signal + b * L_;

  float val[8];
  unsigned int key[8];
#pragma unroll
  for (int i = 0; i < 8; ++i) {
    val[i] = s[(i << 10) + t];
    const unsigned int u = __float_as_uint(val[i]);
    key[i] = (u & 0x80000000u) ? ~u : (u | 0x80000000u);
  }

  // ---- radix select rank 5733 = floor(0.7*(L-1)) ----
  if (t == 0) { sel_prefix = 0u; sel_rank = 5733; }
  __syncthreads();
  for (int round = 0; round < 4; ++round) {
    reinterpret_cast<unsigned int*>(bins)[t] = 0u;
    __syncthreads();
    const unsigned int pre = sel_prefix;
    const int shift = 24 - 8 * round;
#pragma unroll
    for (int i = 0; i < 8; ++i) {
      if (round == 0 || (key[i] >> (shift + 8)) == pre)
        atomicAdd(&bins[t >> 8][(key[i] >> shift) & 255u], 1u);
    }
    __syncthreads();
    if (t < 256)
      bins[0][t] = bins[0][t] + bins[1][t] + bins[2][t] + bins[3][t];
    __syncthreads();
    if (t < 64) {
      const unsigned int c0 = bins[0][(t << 2) + 0], c1 = bins[0][(t << 2) + 1];
      const unsigned int c2 = bins[0][(t << 2) + 2], c3 = bins[0][(t << 2) + 3];
      const unsigned int lsum = c0 + c1 + c2 + c3;
      unsigned int run = lsum;
#pragma unroll
      for (int off = 1; off < 64; off <<= 1) {
        const unsigned int v = __shfl_up(run, off, 64);
        if (t >= off) run += v;
      }
      const int r = sel_rank;
      if (r >= (int)(run - lsum) && r < (int)run) {
        int rr = r - (int)(run - lsum);
        unsigned int cbin;
        if (rr < (int)c0) { cbin = 0; }
        else if (rr < (int)(c0 + c1)) { cbin = 1; rr -= (int)c0; }
        else if (rr < (int)(c0 + c1 + c2)) { cbin = 2; rr -= (int)(c0 + c1); }
        else { cbin = 3; rr -= (int)(c0 + c1 + c2); }
        sel_rank = rr;
        sel_prefix = (pre << 8) | ((unsigned int)(t << 2) | cbin);
      }
    }
    __syncthreads();
  }
  const unsigned int k0 = sel_prefix;

  // ---- successor: count <=k0 and min of keys > k0 (tie-safe) ----
  {
    int cle = 0;
    unsigned int mgt = 0xFFFFFFFFu;
#pragma unroll
    for (int i = 0; i < 8; ++i) {
      if (key[i] <= k0) ++cle;
      else mgt = min(mgt, key[i]);
    }
#pragma unroll
    for (int off = 1; off < 64; off <<= 1) {
      cle += __shfl_xor(cle, off, 64);
      mgt = min(mgt, (unsigned int)__shfl_xor((int)mgt, off, 64));
    }
    if (lane == 0) { wcnt[wv] = cle; wmin[wv] = mgt; }
    __syncthreads();
    if (t == 0) {
      int C = 0; unsigned int M = 0xFFFFFFFFu;
      for (int g = 0; g < 16; ++g) { C += wcnt[g]; M = min(M, wmin[g]); }
      const unsigned int k1 = (C >= 5735) ? k0 : M;
      const unsigned int u0 = (k0 & 0x80000000u) ? (k0 & 0x7fffffffu) : ~k0;
      const unsigned int u1 = (k1 & 0x80000000u) ? (k1 & 0x7fffffffu) : ~k1;
      const float v0 = __uint_as_float(u0);
      const float v1 = __uint_as_float(u1);
      const float g = 0.7f * 8191.0f - 5733.0f;
      sh_thr = v0 + g * (v1 - v0);
    }
    __syncthreads();
  }
  const float thr = sh_thr;

  // ---- candidate bitmap from register values ----
#pragma unroll
  for (int i = 0; i < 8; ++i) {
    const unsigned long long m = __ballot(val[i] < thr);
    if (lane == 0) cw[(i << 4) + wv] = m;
  }
  {
    const int base = t << 3;
#pragma unroll
    for (int i = 0; i < 8; ++i) nb[base + i] = 0;
  }
  __syncthreads();
  if (t == 0) cw[127] |= (1ull << 63);   // forced candidate at L-1
  __syncthreads();

  // ---- (1) per-64-block transition tables ----
  if (t < 512) {
    const int blk = t >> 2, cls = t & 3;
    tbl[blk][cls] = (signed char)chain_sim(cw[blk], cls);
  }
  __syncthreads();

  // ---- (2) serial 128-step state scan ----
  if (t == 0) {
    int st = 0;
    for (int blk = 0; blk < 128; ++blk) {
      const int bs = blk << 6;
      st_in[blk] = st;
      int pl;
      if (blk == 0) {
        pl = chain_sim(cw[0], 4);
      } else {
        int off = st + 4 - bs;
        if (off < 0) off = 0;
        pl = tbl[blk][off];
      }
      if (pl >= 0) st = bs + pl;
    }
  }
  __syncthreads();

  // ---- (3) parallel emission of acceptance + split bytes ----
  if (t < 128) {
    const int bs = t << 6;
    const unsigned long long w = cw[t];
    int st = st_in[t];
    int from = st + 4 - bs;
    if (from < 0) from = 0;
    while (from < 64) {
      const unsigned long long m = w & (~0ull << from);
      if (m == 0ull) break;
      const int p_rel = __ffsll(m) - 1;
      const int p = bs + p_rel;
      nb[p] = 1;
      const int ps = p - st;
      const int k = (ps + 15) >> 4;
      if (k > 1) {
        int sz = ps / k; if (sz < 1) sz = 1;
        for (int j = 1; j < k; ++j) nb[st + j * sz] = 1;
      }
      st = p;
      from = p_rel + 4;
    }
  }
  __syncthreads();

  // ---- prefix scan -> starts / nlast / bounds ----
  if (t < 256) {
    const int base = t << 5;
    int ls = 0;
    for (int i = 0; i < 32; ++i) ls += nb[base + i];
    tsum[t] = ls;
  }
  __syncthreads();
  if (t == 0) {
    int r = 0;
    for (int i = 0; i < 256; ++i) { offs[i] = r; r += tsum[i]; }
    offs[256] = r;
  }
  __syncthreads();
  if (t < 256) {
    const int base = t << 5;
    int run = offs[t];
    for (int i = 0; i < 32; ++i) {
      run += nb[base + i];
      if (nb[base + i]) starts[b * L_ + run] = base + i;
    }
  }
  if (t == 0) { starts[b * L_ + 0] = 0; nlast[b] = offs[256]; }
  __syncthreads();
  const int total = offs[256];
  for (int i = t; i < L_; i += 1024)
    bounds[b * L_ + i] = (i >= 1 && i <= total) ? 1.0f : 0.0f;
}

// ---------------------------------------------------------------------------
// Segment softmax-merge: one wave per segment id; dead sids write zeros.
// ---------------------------------------------------------------------------
__global__ __launch_bounds__(64) void k_merge(const float* __restrict__ x,
    const float* __restrict__ mask, const float* __restrict__ e,
    const int* __restrict__ starts, const int* __restrict__ nlast,
    float* __restrict__ merged)
{
  const int idx = blockIdx.x;
  const int b   = idx >> 13;
  const int sid = idx & (L_ - 1);
  const int n = nlast[b];
  const int lane = threadIdx.x;
  const int c0 = lane << 3;
  float* o = merged + (size_t)(b * L_ + sid) * D_ + c0;
  if (sid > n) {
    const float4 z = make_float4(0.f, 0.f, 0.f, 0.f);
    reinterpret_cast<float4*>(o)[0] = z;
    reinterpret_cast<float4*>(o)[1] = z;
    return;
  }
  const int t0 = starts[b * L_ + sid];
  const int t1 = (sid < n) ? starts[b * L_ + sid + 1] : L_;
  const float* eb = e + b * L_;

  float mx = -INFINITY;
  for (int p = t0; p < t1; ++p) mx = fmaxf(mx, eb[p]);
  float den = 0.f;
  for (int p = t0; p < t1; ++p) den += expf(eb[p] - mx);

  float acc[8] = {0,0,0,0,0,0,0,0};
  for (int p = t0; p < t1; ++p) {
    const float wn = expf(eb[p] - mx) / den;
    const float sc = wn * mask[b * L_ + p];
    const float* xr = x + ((size_t)(b * L_ + p)) * D_ + c0;
    const float4 u0 = reinterpret_cast<const float4*>(xr)[0];
    const float4 u1 = reinterpret_cast<const float4*>(xr)[1];
    acc[0] = fmaf(sc, u0.x, acc[0]); acc[1] = fmaf(sc, u0.y, acc[1]);
    acc[2] = fmaf(sc, u0.z, acc[2]); acc[3] = fmaf(sc, u0.w, acc[3]);
    acc[4] = fmaf(sc, u1.x, acc[4]); acc[5] = fmaf(sc, u1.y, acc[5]);
    acc[6] = fmaf(sc, u1.z, acc[6]); acc[7] = fmaf(sc, u1.w, acc[7]);
  }
  reinterpret_cast<float4*>(o)[0] = make_float4(acc[0], acc[1], acc[2], acc[3]);
  reinterpret_cast<float4*>(o)[1] = make_float4(acc[4], acc[5], acc[6], acc[7]);
}

// ---------------------------------------------------------------------------
extern "C" void kernel_launch(void* const* d_in, const int* in_sizes, int n_in,
                              void* d_out, int out_size, void* d_ws, size_t ws_size,
                              hipStream_t stream) {
  (void)in_sizes; (void)n_in; (void)out_size; (void)ws_size;
  const float* x    = (const float*)d_in[0];
  const float* mask = (const float*)d_in[1];
  const float* W1   = (const float*)d_in[2];
  const float* b1   = (const float*)d_in[3];
  const float* W2   = (const float*)d_in[4];
  const float* b2   = (const float*)d_in[5];
  const float* Wc   = (const float*)d_in[6];
  const float* bc   = (const float*)d_in[7];
  const float* Wb1  = (const float*)d_in[8];
  const float* bb1  = (const float*)d_in[9];
  const float* Wb2  = (const float*)d_in[10];
  const float* bb2  = (const float*)d_in[11];

  float* merged = (float*)d_out;
  float* bounds = (float*)d_out + (size_t)BL_ * D_;

  char* ws = (char*)d_ws;
  float* signal = (float*)(ws);
  float* e      = (float*)(ws + (size_t)BL_ * 4);
  int*   starts = (int*)  (ws + (size_t)BL_ * 8);
  int*   nlast  = (int*)  (ws + (size_t)BL_ * 12);

  k_signal<<<BL_ / TOK, 256, 0, stream>>>(x, mask, W1, b1, W2, b2, Wc, bc,
                                          Wb1, bb1, Wb2, bb2, signal, e);
  k_select<<<B_, 1024, 0, stream>>>(signal, starts, nlast, bounds);
  k_merge<<<BL_, 64, 0, stream>>>(x, mask, e, starts, nlast, merged);
}